// Round 10
// baseline (56.250 us; speedup 1.0000x reference)
//
#include <hip/hip_runtime.h>

#define RNK 32
#define VOC 32000
#define BSZ 512
#define SEQ 24
#define HSEQ 12

#define LEFT_BLOCKS  BSZ
#define CHAIN_BLOCKS (2 * BSZ)            // 1024: [0,512) left, [512,1024) right
#define RED_CHUNKS 125
#define REDUCE_BLOCKS (32 * RED_CHUNKS)   // 4000
#define BLOCK 128

typedef const __attribute__((address_space(1))) void* as1_cvp;
typedef __attribute__((address_space(3))) void* as3_vp;

// Stage one 32x32 fp32 token matrix (4 KB) global->LDS, quad-XOR swizzled:
// LDS quad [r][c] holds M[r][c ^ (r&7)] (16B quads). Source-side swizzle is a
// per-lane constant: lane l covers row r = j*8 + l/8, source quad (l&7)^(l/8).
// Reads apply the same XOR (involution; both-sides rule). [R9-proven]
__device__ __forceinline__ void issue_matrix_load(const float* src_tok,  // core + tok*RNK
                                                  float* lds_base, int lane) {
    const int rlo = lane >> 3;                 // 0..7
    const int cq  = ((lane & 7) ^ rlo) * 4;    // swizzled source quad -> float col
    #pragma unroll
    for (int j = 0; j < 4; ++j) {
        const float* src = src_tok + (size_t)(j * 8 + rlo) * ((size_t)VOC * RNK) + cq;
        __builtin_amdgcn_global_load_lds((as1_cvp)src, (as3_vp)(lds_base + j * 256), 16, 0, 0);
    }
}

// ---------------------------------------------------------------------------
// Fused kernel, 128-thread (2-wave) blocks, 48 KB LDS (3 blocks/CU).
//  - Blocks [0,1024): half-chain (left: v=alpha*M_0..11; right: w=M_23..12*beta).
//    VOLLEY gather: wave w issues ALL its 6 matrices (24 gl_lds) back-to-back,
//    -> ~1150 scattered lines in flight per CU (MLP experiment). Then one
//    vmcnt(0)+barrier and a short serial 12-step compute from LDS.
//  - Blocks [1024, ...): streaming reduce gm[r][s] = sum_v core[r][v][s].
// ---------------------------------------------------------------------------
__global__ __launch_bounds__(BLOCK) void fused_kernel(const float* __restrict__ core,
                                                      const int* __restrict__ y,
                                                      const float* __restrict__ alpha,
                                                      const float* __restrict__ beta,
                                                      float* __restrict__ Lv,
                                                      float* __restrict__ Rv,
                                                      float* __restrict__ gm) {
    __shared__ float mbuf[HSEQ * 1024];       // 48 KB: 12 matrix slots
    const int tid  = threadIdx.x;
    const int lane = tid & 63;
    const int w    = tid >> 6;                // wave 0/1

    if (blockIdx.x < CHAIN_BLOCKS) {
        const bool right = blockIdx.x >= LEFT_BLOCKS;
        const int  row   = blockIdx.x - (right ? LEFT_BLOCKS : 0);
        const int  s     = lane & 31;
        const int  half  = lane >> 5;

        // token stream: left walks 0..11, right walks 23..12
        int ytok = 0;
        if (lane < HSEQ) ytok = y[row * SEQ + (right ? (SEQ - 1 - lane) : lane)];

        float state = right ? beta[s] : alpha[s];   // replicated in both halves

        // Precomputed swizzled LDS float-offsets for the 16 reads per step [R9]:
        // left : read M[r=16h+i][s]   -> r*32 + (((s>>2)^(r&7))<<2) + (s&3)
        // right: read M[j=s][c=16h+i] -> s*32 + (((4h+(i>>2))^(s&7))<<2) + (i&3)
        int la[16];
        if (!right) {
            #pragma unroll
            for (int i = 0; i < 16; ++i) {
                const int r = half * 16 + i;
                la[i] = r * 32 + (((s >> 2) ^ (r & 7)) << 2) + (s & 3);
            }
        } else {
            #pragma unroll
            for (int i = 0; i < 16; ++i) {
                la[i] = s * 32 + (((half * 4 + (i >> 2)) ^ (s & 7)) << 2) + (i & 3);
            }
        }

        // ---- VOLLEY: wave w issues matrices 6w..6w+5 back-to-back ----
        #pragma unroll
        for (int pt = 0; pt < 6; ++pt) {
            const int slot = 6 * w + pt;
            const int tok  = __shfl(ytok, slot, 64);
            issue_matrix_load(core + (size_t)tok * RNK, mbuf + slot * 1024, lane);
        }
        asm volatile("s_waitcnt vmcnt(0)" ::: "memory");
        __syncthreads();                      // all 12 slots complete

        // ---- serial 12-step compute from LDS (both waves, identical) ----
        #pragma unroll
        for (int t = 0; t < HSEQ; ++t) {
            const float* M = mbuf + t * 1024;
            float a0 = 0.f, a1 = 0.f, a2 = 0.f, a3 = 0.f;
            #pragma unroll
            for (int i = 0; i < 16; i += 4) {
                a0 = fmaf(__shfl(state, half * 16 + i + 0, 64), M[la[i + 0]], a0);
                a1 = fmaf(__shfl(state, half * 16 + i + 1, 64), M[la[i + 1]], a1);
                a2 = fmaf(__shfl(state, half * 16 + i + 2, 64), M[la[i + 2]], a2);
                a3 = fmaf(__shfl(state, half * 16 + i + 3, 64), M[la[i + 3]], a3);
            }
            const float acc = (a0 + a1) + (a2 + a3);
            state = acc + __shfl_xor(acc, 32, 64);    // cross-half combine, re-replicate
        }

        if (tid < 32) (right ? Rv : Lv)[row * RNK + tid] = state;
    } else {
        // ---------------- reduce role: gm[r][s] += sum_v core[r][v][s] ----------------
        const int bid   = blockIdx.x - CHAIN_BLOCKS;
        const int r     = bid & 31;
        const int chunk = bid >> 5;           // 0..124

        const float4* slab = (const float4*)(core + (size_t)r * VOC * RNK);
        const int base = chunk * 2048 + tid;  // float4 index; 32 KB per block

        float a0 = 0.f, a1 = 0.f, a2 = 0.f, a3 = 0.f;
        #pragma unroll
        for (int i = 0; i < 16; ++i) {
            float4 v = slab[base + i * 128];
            a0 += v.x; a1 += v.y; a2 += v.z; a3 += v.w;
        }

        // s-phase (tid*4)%32 = (tid&7)*4 invariant under xor 8/16/32: per-wave butterfly.
        #pragma unroll
        for (int mask = 8; mask <= 32; mask <<= 1) {
            a0 += __shfl_xor(a0, mask, 64);
            a1 += __shfl_xor(a1, mask, 64);
            a2 += __shfl_xor(a2, mask, 64);
            a3 += __shfl_xor(a3, mask, 64);
        }
        if ((tid & 63) < 8) {                 // lanes 0-7 of each wave
            const int s0 = (tid & 7) * 4;
            atomicAdd(&gm[r * RNK + s0 + 0], a0);
            atomicAdd(&gm[r * RNK + s0 + 1], a1);
            atomicAdd(&gm[r * RNK + s0 + 2], a2);
            atomicAdd(&gm[r * RNK + s0 + 3], a3);
        }
    }
}

// ---------------------------------------------------------------------------
// Join: p[row] = dot(Lv[row], Rv[row]); block 64 also computes z from gm.
// ---------------------------------------------------------------------------
__global__ __launch_bounds__(256) void dotz_kernel(const float* __restrict__ Lv,
                                                   const float* __restrict__ Rv,
                                                   const float* __restrict__ gm,
                                                   const float* __restrict__ alpha,
                                                   const float* __restrict__ beta,
                                                   float* __restrict__ out) {
    if (blockIdx.x < 64) {
        const int row = blockIdx.x * 8 + (threadIdx.x >> 5);   // 8 rows/block
        const int l   = threadIdx.x & 31;
        float v = Lv[row * RNK + l] * Rv[row * RNK + l];
        #pragma unroll
        for (int m = 16; m >= 1; m >>= 1) v += __shfl_xor(v, m, 64);  // stays in 32-group
        if (l == 0) out[row] = v;
    } else if (threadIdx.x < 64) {
        const int s    = threadIdx.x & 31;
        const int half = threadIdx.x >> 5;
        float col[16];
        #pragma unroll
        for (int i = 0; i < 16; ++i) col[i] = gm[(half * 16 + i) * RNK + s];
        float v = alpha[s];
        #pragma unroll
        for (int t = 0; t < SEQ; ++t) {
            float a0 = 0.f, a1 = 0.f, a2 = 0.f, a3 = 0.f;
            #pragma unroll
            for (int i = 0; i < 16; i += 4) {
                a0 = fmaf(__shfl(v, half * 16 + i + 0, 64), col[i + 0], a0);
                a1 = fmaf(__shfl(v, half * 16 + i + 1, 64), col[i + 1], a1);
                a2 = fmaf(__shfl(v, half * 16 + i + 2, 64), col[i + 2], a2);
                a3 = fmaf(__shfl(v, half * 16 + i + 3, 64), col[i + 3], a3);
            }
            const float acc = (a0 + a1) + (a2 + a3);
            v = acc + __shfl_xor(acc, 32, 64);
        }
        float z = v * beta[s];
        #pragma unroll
        for (int m = 16; m >= 1; m >>= 1) z += __shfl_xor(z, m, 64);
        if (threadIdx.x == 0) out[BSZ] = z * (float)BSZ;
    }
}

extern "C" void kernel_launch(void* const* d_in, const int* in_sizes, int n_in,
                              void* d_out, int out_size, void* d_ws, size_t ws_size,
                              hipStream_t stream) {
    const int*   y     = (const int*)d_in[0];
    const float* alpha = (const float*)d_in[1];
    const float* beta  = (const float*)d_in[2];
    const float* core  = (const float*)d_in[3];
    float* out = (float*)d_out;
    float* gm  = (float*)d_ws;                 // 1024 floats
    float* Lv  = gm + RNK * RNK;               // 512*32
    float* Rv  = Lv + BSZ * RNK;               // 512*32

    hipMemsetAsync(gm, 0, RNK * RNK * sizeof(float), stream);
    fused_kernel<<<CHAIN_BLOCKS + REDUCE_BLOCKS, BLOCK, 0, stream>>>(
        core, y, alpha, beta, Lv, Rv, gm);
    dotz_kernel<<<65, 256, 0, stream>>>(Lv, Rv, gm, alpha, beta, out);
}